// Round 3
// baseline (978.688 us; speedup 1.0000x reference)
//
#include <hip/hip_runtime.h>

typedef __bf16 bf16x8 __attribute__((ext_vector_type(8)));
typedef float f32x4 __attribute__((ext_vector_type(4)));

static __device__ __forceinline__ unsigned short f2bf(float f) {
    unsigned u = __builtin_bit_cast(unsigned, f);
    unsigned r = u + 0x7fffu + ((u >> 16) & 1u);   // RNE; inputs finite
    return (unsigned short)(r >> 16);
}

static __device__ __forceinline__ float fsig(float x) {
    return 1.f / (1.f + __expf(-x));
}
static __device__ __forceinline__ float ftanh(float x) {
    return 1.f - 2.f / (1.f + __expf(2.f * x));
}

#define GLD_LDS16(g, l) __builtin_amdgcn_global_load_lds( \
    (const __attribute__((address_space(1))) unsigned int*)(const void*)(g), \
    (__attribute__((address_space(3))) unsigned int*)(void*)(l), 16, 0, 0)

// ---------------- prep: fp32->bf16 converts, embedding gather, zeros ----------
__global__ __launch_bounds__(256) void k_prep(
    const float* Wih, const float* Whh, const float* Wh, const float* Wc,
    const float* Wout, const float* emb, const int* targets,
    unsigned short* Wih_b, unsigned short* Whh_b, unsigned short* Wh_b,
    unsigned short* Wc_b, unsigned short* Wout_b, unsigned short* Aemb,
    float* out, int* ctrs, float* ps)
{
    const long N0 = 1048576, N1 = 1048576, N2 = 1048576, N3 = 1048576;
    const long N4 = 5120000, N5 = 2064384, N6 = 640000, N7 = 256, N8 = 65536;
    const long total = N0 + N1 + N2 + N3 + N4 + N5 + N6 + N7 + N8;
    const long stride = (long)gridDim.x * blockDim.x;
    for (long i = (long)blockIdx.x * blockDim.x + threadIdx.x; i < total; i += stride) {
        long j = i;
        if (j < N0) { Wih_b[j] = f2bf(Wih[j]); continue; } j -= N0;
        if (j < N1) { Whh_b[j] = f2bf(Whh[j]); continue; } j -= N1;
        if (j < N2) { Wh_b[j]  = f2bf(Wh[j]);  continue; } j -= N2;
        if (j < N3) { Wc_b[j]  = f2bf(Wc[j]);  continue; } j -= N3;
        if (j < N4) { Wout_b[j] = f2bf(Wout[j]); continue; } j -= N4;
        if (j < N5) {  // gathered embeddings: row m = b*63+t -> targets[b*64+t]
            long m = j >> 9; int k = (int)(j & 511);
            int b = (int)(m / 63), t = (int)(m - (long)b * 63);
            int row = targets[b * 64 + t];
            Aemb[j] = f2bf(emb[(long)row * 512 + k]);
            continue;
        } j -= N5;
        if (j < N6) {  // zero d_out[:, 0, :]
            long b = j / 10000, v = j - b * 10000;
            out[b * 640000 + v] = 0.f;
            continue;
        } j -= N6;
        if (j < N7) { ctrs[j] = 0; continue; } j -= N7;
        ps[j] = 0.f;
    }
}

// ---------------- mean over P=196, store bf16 [64][2048] ----------------------
__global__ __launch_bounds__(128) void k_mean(const float* enc, unsigned short* mean_b)
{
    int b = blockIdx.y;
    int c = blockIdx.x * 128 + threadIdx.x;
    const float* base = enc + (long)b * 196 * 2048 + c;
    float s0 = 0.f, s1 = 0.f, s2 = 0.f, s3 = 0.f;
    for (int p = 0; p < 196; p += 4) {
        s0 += base[(long)(p + 0) * 2048];
        s1 += base[(long)(p + 1) * 2048];
        s2 += base[(long)(p + 2) * 2048];
        s3 += base[(long)(p + 3) * 2048];
    }
    mean_b[(long)b * 2048 + c] = f2bf((s0 + s1 + s2 + s3) * (1.f / 196.f));
}

// ---------------- h0/c0 partials: split-K x4, fp32 atomic accumulate ----------
__global__ __launch_bounds__(256) void k_h0c0(
    const unsigned short* A, const unsigned short* Whb, const unsigned short* Wcb,
    float* ps)
{
    __shared__ unsigned short As[64 * 40];
    __shared__ unsigned short Bs[64 * 40];
    const int tid = threadIdx.x;
    const int n0 = blockIdx.x * 64;
    const int kc = blockIdx.y * 16;
    const int w = tid >> 6, lane = tid & 63, quad = lane >> 4, l16 = lane & 15;
    const int r = tid >> 2, seg = tid & 3;
    f32x4 acc[4];
#pragma unroll
    for (int i = 0; i < 4; i++) acc[i] = (f32x4){0.f, 0.f, 0.f, 0.f};

    for (int kb = kc; kb < kc + 16; kb++) {
        int k0 = kb * 32;
        *(uint4*)&As[r * 40 + seg * 8] = *(const uint4*)&A[(long)r * 2048 + k0 + seg * 8];
        int ngr = n0 + r;
        const unsigned short* bsrc = (ngr < 512) ? (Whb + (long)ngr * 2048)
                                                 : (Wcb + (long)(ngr - 512) * 2048);
        *(uint4*)&Bs[r * 40 + seg * 8] = *(const uint4*)&bsrc[k0 + seg * 8];
        __syncthreads();
        bf16x8 bfr = *(const bf16x8*)&Bs[(16 * w + l16) * 40 + quad * 8];
#pragma unroll
        for (int mt = 0; mt < 4; mt++) {
            bf16x8 af = *(const bf16x8*)&As[(mt * 16 + l16) * 40 + quad * 8];
            acc[mt] = __builtin_amdgcn_mfma_f32_16x16x32_bf16(af, bfr, acc[mt], 0, 0, 0);
        }
        __syncthreads();
    }
    int ng = n0 + 16 * w + l16;
#pragma unroll
    for (int mt = 0; mt < 4; mt++) {
#pragma unroll
        for (int rr = 0; rr < 4; rr++) {
            int m = mt * 16 + quad * 4 + rr;
            atomicAdd(&ps[(long)m * 1024 + ng], acc[mt][rr]);
        }
    }
}

// ---------------- h0/c0 finalize: tanh(ps + bias) -> Hbuf[0] / c0buf ----------
__global__ __launch_bounds__(256) void k_fin(
    const float* ps, const float* bh, const float* bc,
    unsigned short* Hbuf, float* c0buf)
{
    int i = blockIdx.x * 256 + threadIdx.x;   // 65536 = 64 x 1024
    int m = i >> 10, ng = i & 1023;
    int j = ng & 511;
    float bias = (ng < 512) ? bh[j] : bc[j];
    float v = tanhf(ps[i] + bias);
    if (ng < 512) Hbuf[(long)m * 512 + j] = f2bf(v);
    else          c0buf[(long)m * 512 + j] = v;
}

// ---------------- xg: [4032x512] @ [2048x512]^T + biases, fp32 out ------------
__global__ __launch_bounds__(256) void k_xg(
    const unsigned short* A, const unsigned short* Bw,
    const float* bih, const float* bhh, float* xg)
{
    __shared__ unsigned short As[128 * 32];
    __shared__ unsigned short Bs[128 * 32];
    const int tid = threadIdx.x;
    const int n0 = blockIdx.x * 128, m0 = blockIdx.y * 128;
    const int w = tid >> 6, lane = tid & 63, quad = lane >> 4, l16 = lane & 15;
    const int wm = w >> 1, wn = w & 1;
    const int gr = lane >> 2, gc = (lane & 3) * 8;

    f32x4 acc[4][4];
#pragma unroll
    for (int i = 0; i < 4; i++)
#pragma unroll
        for (int j = 0; j < 4; j++) acc[i][j] = (f32x4){0.f, 0.f, 0.f, 0.f};

    for (int kb = 0; kb < 16; kb++) {
        int k0 = kb * 32;
#pragma unroll
        for (int p = 0; p < 2; p++) {
            int rowa = m0 + p * 64 + w * 16 + gr;
            GLD_LDS16(A + (long)rowa * 512 + k0 + gc, As + (p * 64 + w * 16) * 32);
            int rowb = n0 + p * 64 + w * 16 + gr;
            GLD_LDS16(Bw + (long)rowb * 512 + k0 + gc, Bs + (p * 64 + w * 16) * 32);
        }
        __syncthreads();
        bf16x8 af[4], bf[4];
#pragma unroll
        for (int mt = 0; mt < 4; mt++)
            af[mt] = *(const bf16x8*)&As[(wm * 64 + mt * 16 + l16) * 32 + quad * 8];
#pragma unroll
        for (int nt = 0; nt < 4; nt++)
            bf[nt] = *(const bf16x8*)&Bs[(wn * 64 + nt * 16 + l16) * 32 + quad * 8];
#pragma unroll
        for (int mt = 0; mt < 4; mt++)
#pragma unroll
            for (int nt = 0; nt < 4; nt++)
                acc[mt][nt] = __builtin_amdgcn_mfma_f32_16x16x32_bf16(af[mt], bf[nt], acc[mt][nt], 0, 0, 0);
        __syncthreads();
    }
#pragma unroll
    for (int nt = 0; nt < 4; nt++) {
        int n = n0 + wn * 64 + nt * 16 + l16;
        float bias = bih[n] + bhh[n];
#pragma unroll
        for (int mt = 0; mt < 4; mt++) {
#pragma unroll
            for (int rr = 0; rr < 4; rr++) {
                int r = m0 + wm * 64 + mt * 16 + quad * 4 + rr;
                if (r < 4032) xg[(long)r * 2048 + n] = acc[mt][nt][rr] + bias;
            }
        }
    }
}

// ---------------- fused scan + logits -----------------------------------------
// Blocks 0..127: scan (4 batch-groups x 32 hidden-slices of 16 units; W slice
//   65KB LDS -> 2 blocks/CU so logits tiles can co-reside). R0-proven lockstep
//   protocol: barriers + per-group step counter, 1 poller/block, ctr target s*32.
//   h gathered direct to MFMA registers (readiness guaranteed by ctr; loads
//   issued exactly once - no polling).
// Blocks 128..2655: logits tiles (ascending s order). Each waits (1 thread,
//   s_sleep-paced) until all 4 group ctrs reach s_hi*32, then runs the m97-style
//   128x128 GEMM. Early tiles compute while the scan is still running.
__global__ __launch_bounds__(256, 2) void k_scan_out(
    const unsigned short* Whh_b, const float* xg, const float* c0buf,
    unsigned short* Hbuf, int* ctrs,
    const unsigned short* Wob, const float* bout, float* out)
{
    __shared__ __align__(16) char smem[70976];
    const int tid = threadIdx.x;
    const int bid = blockIdx.x;

    if (bid < 128) {
        // ================= scan path =================
        unsigned short* Wlds = (unsigned short*)smem;          // 64*520*2 = 66560
        float* gs = (float*)(smem + 66560);                    // 16*69*4  = 4416
        const int grp = bid & 3;
        const int b0 = grp * 16;          // batch group
        const int slice = bid >> 2;       // 0..31
        const int j0 = slice * 16;        // hidden-unit slice
        const int w = tid >> 6, lane = tid & 63, quad = lane >> 4, l16 = lane & 15;
        const int gm = tid >> 3, gu0 = (tid & 7) * 2;   // gates: tid<128

        // W_hh slice: local row nrel = q*16+u  <->  W_hh row q*512 + j0 + u
        // wave w ends up owning gate q=w (local rows 16w..16w+15)
        for (int nrel = w; nrel < 64; nrel += 4) {
            int q = nrel >> 4, u = nrel & 15;
            *(uint4*)&Wlds[nrel * 520 + lane * 8] =
                *(const uint4*)&Whh_b[(long)(q * 512 + j0 + u) * 512 + lane * 8];
        }
        float c0v = 0.f, c1v = 0.f;
        if (tid < 128) {
            float2 cr = *(const float2*)&c0buf[(long)(b0 + gm) * 512 + j0 + gu0];
            c0v = cr.x; c1v = cr.y;
        }
        int* ctr = ctrs + grp * 64;
        __syncthreads();

        for (int s = 1; s < 64; s++) {
            float2 xv0 = {0.f, 0.f}, xv1 = {0.f, 0.f}, xv2 = {0.f, 0.f}, xv3 = {0.f, 0.f};
            if (tid < 128) {
                const float* xb = xg + ((long)(b0 + gm) * 63 + (s - 1)) * 2048 + j0 + gu0;
                xv0 = *(const float2*)(xb + 0);
                xv1 = *(const float2*)(xb + 512);
                xv2 = *(const float2*)(xb + 1024);
                xv3 = *(const float2*)(xb + 1536);
            }
            // A fragments straight from coherence point (h[s-1] ready by ctr):
            // lane (l16,quad): batch b0+l16, cols kk*32 + quad*8 .. +8
            const unsigned long long* hsrc = (const unsigned long long*)Hbuf
                + ((long)(s - 1) * 64 + b0 + l16) * 128 + quad * 2;
            unsigned long long hv[32];
#pragma unroll
            for (int kk = 0; kk < 16; kk++) {
                hv[kk * 2 + 0] = __hip_atomic_load(hsrc + kk * 8 + 0, __ATOMIC_RELAXED,
                                                   __HIP_MEMORY_SCOPE_AGENT);
                hv[kk * 2 + 1] = __hip_atomic_load(hsrc + kk * 8 + 1, __ATOMIC_RELAXED,
                                                   __HIP_MEMORY_SCOPE_AGENT);
            }
            f32x4 acc = (f32x4){0.f, 0.f, 0.f, 0.f};
#pragma unroll
            for (int kk = 0; kk < 16; kk++) {
                union { unsigned long long u[2]; bf16x8 v; } a;
                a.u[0] = hv[kk * 2 + 0];
                a.u[1] = hv[kk * 2 + 1];
                bf16x8 bB = *(const bf16x8*)&Wlds[(16 * w + l16) * 520 + kk * 32 + quad * 8];
                acc = __builtin_amdgcn_mfma_f32_16x16x32_bf16(a.v, bB, acc, 0, 0, 0);
            }
            // gs[batch][local gate row]: gate row = 16w + l16, batch = quad*4+rr
#pragma unroll
            for (int rr = 0; rr < 4; rr++)
                gs[(quad * 4 + rr) * 69 + 16 * w + l16] = acc[rr];
            __syncthreads();

            if (tid < 128) {
                float gi0 = gs[gm * 69 + gu0]          + xv0.x;
                float gi1 = gs[gm * 69 + gu0 + 1]      + xv0.y;
                float gf0 = gs[gm * 69 + 16 + gu0]     + xv1.x;
                float gf1 = gs[gm * 69 + 17 + gu0]     + xv1.y;
                float gg0 = gs[gm * 69 + 32 + gu0]     + xv2.x;
                float gg1 = gs[gm * 69 + 33 + gu0]     + xv2.y;
                float go0 = gs[gm * 69 + 48 + gu0]     + xv3.x;
                float go1 = gs[gm * 69 + 49 + gu0]     + xv3.y;
                float cn0 = fsig(gf0) * c0v + fsig(gi0) * ftanh(gg0);
                float cn1 = fsig(gf1) * c1v + fsig(gi1) * ftanh(gg1);
                c0v = cn0; c1v = cn1;
                float h0v = fsig(go0) * ftanh(cn0);
                float h1v = fsig(go1) * ftanh(cn1);
                unsigned hp = (unsigned)f2bf(h0v) | ((unsigned)f2bf(h1v) << 16);
                __hip_atomic_store((unsigned*)(Hbuf + ((long)s * 64 + b0 + gm) * 512 + j0 + gu0),
                                   hp, __ATOMIC_RELAXED, __HIP_MEMORY_SCOPE_AGENT);
            }
            __syncthreads();   // drains vmcnt(0): all waves' h stores complete
            if (s < 63) {
                if (tid == 0) {
                    __hip_atomic_fetch_add(ctr, 1, __ATOMIC_RELEASE, __HIP_MEMORY_SCOPE_AGENT);
                    int target = s * 32;
                    while (__hip_atomic_load(ctr, __ATOMIC_RELAXED, __HIP_MEMORY_SCOPE_AGENT)
                           < target) {}
                }
                __syncthreads();
            } else {
                if (tid == 0)   // completion signal for logits waiters
                    __hip_atomic_fetch_add(ctr, 1, __ATOMIC_RELEASE, __HIP_MEMORY_SCOPE_AGENT);
            }
        }
        return;
    }

    // ================= logits path =================
    unsigned short* As = (unsigned short*)smem;            // 128*32*2 = 8192
    unsigned short* Bs = (unsigned short*)(smem + 8192);   // 128*32*2 = 8192
    const int lid = bid - 128;
    const int m_idx = lid / 79, n_idx = lid - m_idx * 79;  // ascending s order
    const int m0 = m_idx * 128, n0 = n_idx * 128;
    const unsigned short* A = Hbuf + 64 * 512;             // A row r = Hbuf row r+64

    {   // wait until h[s] available for all rows of this tile, all 4 groups
        int s_hi = 2 * m_idx + 2; if (s_hi > 63) s_hi = 63;
        const int target = s_hi * 32;
        if (tid == 0) {
            for (;;) {
                int a0 = __hip_atomic_load(ctrs + 0,   __ATOMIC_RELAXED, __HIP_MEMORY_SCOPE_AGENT);
                int a1 = __hip_atomic_load(ctrs + 64,  __ATOMIC_RELAXED, __HIP_MEMORY_SCOPE_AGENT);
                int a2 = __hip_atomic_load(ctrs + 128, __ATOMIC_RELAXED, __HIP_MEMORY_SCOPE_AGENT);
                int a3 = __hip_atomic_load(ctrs + 192, __ATOMIC_RELAXED, __HIP_MEMORY_SCOPE_AGENT);
                if (a0 >= target && a1 >= target && a2 >= target && a3 >= target) break;
                __builtin_amdgcn_s_sleep(32);
            }
        }
        __syncthreads();
        asm volatile("" ::: "memory");
    }

    const int w = tid >> 6, lane = tid & 63, quad = lane >> 4, l16 = lane & 15;
    const int wm = w >> 1, wn = w & 1;
    const int gr = lane >> 2, gc = (lane & 3) * 8;

    f32x4 acc[4][4];
#pragma unroll
    for (int i = 0; i < 4; i++)
#pragma unroll
        for (int j = 0; j < 4; j++) acc[i][j] = (f32x4){0.f, 0.f, 0.f, 0.f};

    for (int kb = 0; kb < 16; kb++) {
        int k0 = kb * 32;
#pragma unroll
        for (int p = 0; p < 2; p++) {
            int rowa = m0 + p * 64 + w * 16 + gr;
            GLD_LDS16(A + (long)rowa * 512 + k0 + gc, As + (p * 64 + w * 16) * 32);
            int rowb = n0 + p * 64 + w * 16 + gr;
            GLD_LDS16(Wob + (long)rowb * 512 + k0 + gc, Bs + (p * 64 + w * 16) * 32);
        }
        __syncthreads();
        bf16x8 af[4], bf[4];
#pragma unroll
        for (int mt = 0; mt < 4; mt++)
            af[mt] = *(const bf16x8*)&As[(wm * 64 + mt * 16 + l16) * 32 + quad * 8];
#pragma unroll
        for (int nt = 0; nt < 4; nt++)
            bf[nt] = *(const bf16x8*)&Bs[(wn * 64 + nt * 16 + l16) * 32 + quad * 8];
#pragma unroll
        for (int mt = 0; mt < 4; mt++)
#pragma unroll
            for (int nt = 0; nt < 4; nt++)
                acc[mt][nt] = __builtin_amdgcn_mfma_f32_16x16x32_bf16(af[mt], bf[nt], acc[mt][nt], 0, 0, 0);
        __syncthreads();
    }
#pragma unroll
    for (int nt = 0; nt < 4; nt++) {
        int n = n0 + wn * 64 + nt * 16 + l16;
        if (n >= 10000) continue;
        float bias = bout[n];
#pragma unroll
        for (int mt = 0; mt < 4; mt++) {
#pragma unroll
            for (int rr = 0; rr < 4; rr++) {
                int r = m0 + wm * 64 + mt * 16 + quad * 4 + rr;  // A row
                if (r < 4032) {
                    int s = (r >> 6) + 1, b = r & 63;
                    out[((long)b * 64 + s) * 10000 + n] = acc[mt][nt][rr] + bias;
                }
            }
        }
    }
}

extern "C" void kernel_launch(void* const* d_in, const int* in_sizes, int n_in,
                              void* d_out, int out_size, void* d_ws, size_t ws_size,
                              hipStream_t stream)
{
    const float* enc     = (const float*)d_in[0];
    const int*   targets = (const int*)d_in[1];
    const float* emb     = (const float*)d_in[2];
    const float* Wih     = (const float*)d_in[3];
    const float* Whh     = (const float*)d_in[4];
    const float* bih     = (const float*)d_in[5];
    const float* bhh     = (const float*)d_in[6];
    const float* Wh      = (const float*)d_in[7];
    const float* bh      = (const float*)d_in[8];
    const float* Wc      = (const float*)d_in[9];
    const float* bc      = (const float*)d_in[10];
    const float* Wout    = (const float*)d_in[11];
    const float* bout    = (const float*)d_in[12];
    float* out = (float*)d_out;

    char* ws = (char*)d_ws;
    size_t off = 0;
    auto alloc = [&](size_t bytes) {
        void* p = ws + off;
        off = (off + bytes + 255) & ~(size_t)255;
        return p;
    };
    unsigned short* mean_b = (unsigned short*)alloc((size_t)64 * 2048 * 2);
    unsigned short* Wih_b  = (unsigned short*)alloc((size_t)2048 * 512 * 2);
    unsigned short* Whh_b  = (unsigned short*)alloc((size_t)2048 * 512 * 2);
    unsigned short* Wh_b   = (unsigned short*)alloc((size_t)512 * 2048 * 2);
    unsigned short* Wc_b   = (unsigned short*)alloc((size_t)512 * 2048 * 2);
    unsigned short* Wout_b = (unsigned short*)alloc((size_t)10000 * 512 * 2);
    unsigned short* Aemb   = (unsigned short*)alloc((size_t)(4032 + 64) * 512 * 2);
    float*          xg     = (float*)alloc((size_t)4032 * 2048 * 4);
    unsigned short* Hbuf   = (unsigned short*)alloc((size_t)(64 * 64 + 64) * 512 * 2);
    float*          c0buf  = (float*)alloc((size_t)64 * 512 * 4);
    int*            ctrs   = (int*)alloc(256 * 4);
    float*          ps     = (float*)alloc((size_t)64 * 1024 * 4);

    k_prep<<<4096, 256, 0, stream>>>(Wih, Whh, Wh, Wc, Wout, emb, targets,
                                     Wih_b, Whh_b, Wh_b, Wc_b, Wout_b, Aemb, out, ctrs, ps);
    k_mean<<<dim3(16, 64), 128, 0, stream>>>(enc, mean_b);
    k_h0c0<<<dim3(16, 4), 256, 0, stream>>>(mean_b, Wh_b, Wc_b, ps);
    k_fin<<<256, 256, 0, stream>>>(ps, bh, bc, Hbuf, c0buf);
    k_xg<<<dim3(16, 32), 256, 0, stream>>>(Aemb, Wih_b, bih, bhh, xg);
    // fused: 128 scan blocks first, then 2528 logits tiles in ascending-s order
    k_scan_out<<<128 + 79 * 32, 256, 0, stream>>>(Whh_b, xg, c0buf, Hbuf, ctrs,
                                                  Wout_b, bout, out);
}

// Round 4
// 627.357 us; speedup vs baseline: 1.5600x; 1.5600x over previous
//
#include <hip/hip_runtime.h>

typedef __bf16 bf16x8 __attribute__((ext_vector_type(8)));
typedef float f32x4 __attribute__((ext_vector_type(4)));

static __device__ __forceinline__ unsigned short f2bf(float f) {
    unsigned u = __builtin_bit_cast(unsigned, f);
    unsigned r = u + 0x7fffu + ((u >> 16) & 1u);   // RNE; inputs finite
    return (unsigned short)(r >> 16);
}

#define GLD_LDS16(g, l) __builtin_amdgcn_global_load_lds( \
    (const __attribute__((address_space(1))) unsigned int*)(const void*)(g), \
    (__attribute__((address_space(3))) unsigned int*)(void*)(l), 16, 0, 0)

// ---------------- K1: all independent prep work, region-per-block -------------
// regions: [0,2048) W4 cvt | [2048,4548) Wout cvt | [4548,5556) emb gather |
//          [5556,6181) out zeros | [6181,6246) ps+ctrs | [6246,6758) mean
__global__ __launch_bounds__(256) void k_prep(
    const float* Wih, const float* Whh, const float* Wh, const float* Wc,
    const float* Wout, const float* emb, const int* targets, const float* enc,
    unsigned short* Wih_b, unsigned short* Whh_b, unsigned short* Wh_b,
    unsigned short* Wc_b, unsigned short* Wout_b, unsigned short* Aemb,
    float* out, int* ctrs, float* ps, unsigned short* mean_b)
{
    const int bid = blockIdx.x, tid = threadIdx.x;

    if (bid < 2048) {                      // Wih/Whh/Wh/Wc: 4 x 1048576 floats
        long f = ((long)bid * 256 + tid) * 8;
        int a = (int)(f >> 20);
        long off = f & 1048575;
        const float* s = (a == 0) ? Wih : (a == 1) ? Whh : (a == 2) ? Wh : Wc;
        unsigned short* d = (a == 0) ? Wih_b : (a == 1) ? Whh_b : (a == 2) ? Wh_b : Wc_b;
        float4 v0 = *(const float4*)(s + off);
        float4 v1 = *(const float4*)(s + off + 4);
        unsigned short r[8] = {f2bf(v0.x), f2bf(v0.y), f2bf(v0.z), f2bf(v0.w),
                               f2bf(v1.x), f2bf(v1.y), f2bf(v1.z), f2bf(v1.w)};
        *(uint4*)(d + off) = *(uint4*)r;
        return;
    }
    if (bid < 4548) {                      // Wout: 5,120,000 floats (exact)
        long f = ((long)(bid - 2048) * 256 + tid) * 8;
        float4 v0 = *(const float4*)(Wout + f);
        float4 v1 = *(const float4*)(Wout + f + 4);
        unsigned short r[8] = {f2bf(v0.x), f2bf(v0.y), f2bf(v0.z), f2bf(v0.w),
                               f2bf(v1.x), f2bf(v1.y), f2bf(v1.z), f2bf(v1.w)};
        *(uint4*)(Wout_b + f) = *(uint4*)r;
        return;
    }
    if (bid < 5556) {                      // gather: 4032 rows x 512 (exact)
        unsigned t = (unsigned)(bid - 4548) * 256 + tid;   // < 258048
        unsigned row = t >> 6;                             // 64 threads/row
        unsigned col = (t & 63) * 8;
        unsigned b = row / 63u, tt = row - b * 63u;        // 32-bit magic div
        int trg = targets[b * 64 + tt];
        const float* s = emb + (long)trg * 512 + col;
        float4 v0 = *(const float4*)(s);
        float4 v1 = *(const float4*)(s + 4);
        unsigned short r[8] = {f2bf(v0.x), f2bf(v0.y), f2bf(v0.z), f2bf(v0.w),
                               f2bf(v1.x), f2bf(v1.y), f2bf(v1.z), f2bf(v1.w)};
        *(uint4*)(Aemb + (long)row * 512 + col) = *(uint4*)r;
        return;
    }
    if (bid < 6181) {                      // zero out[:,0,:]: 640,000 floats (exact)
        unsigned idx = ((unsigned)(bid - 5556) * 256 + tid) * 4;
        unsigned b = idx / 10000u, v = idx - b * 10000u;   // 4-chunks never straddle rows
        *(float4*)(out + (long)b * 640000 + v) = (float4){0.f, 0.f, 0.f, 0.f};
        return;
    }
    if (bid < 6246) {                      // ps zeros (64 blocks) + ctrs (1 block)
        int rel = bid - 6181;
        if (rel < 64) {
            unsigned idx = ((unsigned)rel * 256 + tid) * 4;
            *(float4*)(ps + idx) = (float4){0.f, 0.f, 0.f, 0.f};
        } else {
            ctrs[tid] = 0;
        }
        return;
    }
    {                                      // mean over P=196 -> bf16 [64][2048]
        unsigned idx = (unsigned)(bid - 6246) * 256 + tid;  // < 131072
        unsigned b = idx >> 11, c = idx & 2047;
        const float* base = enc + (long)b * 196 * 2048 + c;
        float s0 = 0.f, s1 = 0.f, s2 = 0.f, s3 = 0.f;
        for (int p = 0; p < 196; p += 4) {
            s0 += base[(long)(p + 0) * 2048];
            s1 += base[(long)(p + 1) * 2048];
            s2 += base[(long)(p + 2) * 2048];
            s3 += base[(long)(p + 3) * 2048];
        }
        mean_b[(long)b * 2048 + c] = f2bf((s0 + s1 + s2 + s3) * (1.f / 196.f));
    }
}

// ---------------- K2: h0c0 partials (blocks 0..63) + xg GEMM (64..575) --------
__global__ __launch_bounds__(256) void k_gemm2(
    const unsigned short* mean_b, const unsigned short* Whb, const unsigned short* Wcb,
    float* ps,
    const unsigned short* Aemb, const unsigned short* Wihb,
    const float* bih, const float* bhh, float* xg)
{
    __shared__ __align__(16) char smem[16384];
    const int bid = blockIdx.x, tid = threadIdx.x;
    const int w = tid >> 6, lane = tid & 63, quad = lane >> 4, l16 = lane & 15;

    if (bid < 64) {
        // ---- h0/c0 partials: split-K x4, fp32 atomic accumulate ----
        unsigned short* As = (unsigned short*)smem;            // 64*40*2 = 5120
        unsigned short* Bs = (unsigned short*)(smem + 5120);
        const int n0 = (bid & 15) * 64;
        const int kc = (bid >> 4) * 16;
        const int r = tid >> 2, seg = tid & 3;
        f32x4 acc[4];
#pragma unroll
        for (int i = 0; i < 4; i++) acc[i] = (f32x4){0.f, 0.f, 0.f, 0.f};

        for (int kb = kc; kb < kc + 16; kb++) {
            int k0 = kb * 32;
            *(uint4*)&As[r * 40 + seg * 8] = *(const uint4*)&mean_b[(long)r * 2048 + k0 + seg * 8];
            int ngr = n0 + r;
            const unsigned short* bsrc = (ngr < 512) ? (Whb + (long)ngr * 2048)
                                                     : (Wcb + (long)(ngr - 512) * 2048);
            *(uint4*)&Bs[r * 40 + seg * 8] = *(const uint4*)&bsrc[k0 + seg * 8];
            __syncthreads();
            bf16x8 bfr = *(const bf16x8*)&Bs[(16 * w + l16) * 40 + quad * 8];
#pragma unroll
            for (int mt = 0; mt < 4; mt++) {
                bf16x8 af = *(const bf16x8*)&As[(mt * 16 + l16) * 40 + quad * 8];
                acc[mt] = __builtin_amdgcn_mfma_f32_16x16x32_bf16(af, bfr, acc[mt], 0, 0, 0);
            }
            __syncthreads();
        }
        int ng = n0 + 16 * w + l16;
#pragma unroll
        for (int mt = 0; mt < 4; mt++) {
#pragma unroll
            for (int rr = 0; rr < 4; rr++) {
                int m = mt * 16 + quad * 4 + rr;
                atomicAdd(&ps[(long)m * 1024 + ng], acc[mt][rr]);
            }
        }
        return;
    }

    // ---- xg: [4032x512] @ [2048x512]^T + biases, m97-style 128x128 tile ----
    unsigned short* As = (unsigned short*)smem;                // 128*32*2 = 8192
    unsigned short* Bs = (unsigned short*)(smem + 8192);
    const int rel = bid - 64;
    const int n0 = (rel & 15) * 128, m0 = (rel >> 4) * 128;
    const int wm = w >> 1, wn = w & 1;
    const int gr = lane >> 2, gc = (lane & 3) * 8;

    f32x4 acc[4][4];
#pragma unroll
    for (int i = 0; i < 4; i++)
#pragma unroll
        for (int j = 0; j < 4; j++) acc[i][j] = (f32x4){0.f, 0.f, 0.f, 0.f};

    for (int kb = 0; kb < 16; kb++) {
        int k0 = kb * 32;
#pragma unroll
        for (int p = 0; p < 2; p++) {
            int rowa = m0 + p * 64 + w * 16 + gr;
            GLD_LDS16(Aemb + (long)rowa * 512 + k0 + gc, As + (p * 64 + w * 16) * 32);
            int rowb = n0 + p * 64 + w * 16 + gr;
            GLD_LDS16(Wihb + (long)rowb * 512 + k0 + gc, Bs + (p * 64 + w * 16) * 32);
        }
        __syncthreads();
        bf16x8 af[4], bf[4];
#pragma unroll
        for (int mt = 0; mt < 4; mt++)
            af[mt] = *(const bf16x8*)&As[(wm * 64 + mt * 16 + l16) * 32 + quad * 8];
#pragma unroll
        for (int nt = 0; nt < 4; nt++)
            bf[nt] = *(const bf16x8*)&Bs[(wn * 64 + nt * 16 + l16) * 32 + quad * 8];
#pragma unroll
        for (int mt = 0; mt < 4; mt++)
#pragma unroll
            for (int nt = 0; nt < 4; nt++)
                acc[mt][nt] = __builtin_amdgcn_mfma_f32_16x16x32_bf16(af[mt], bf[nt], acc[mt][nt], 0, 0, 0);
        __syncthreads();
    }
#pragma unroll
    for (int nt = 0; nt < 4; nt++) {
        int n = n0 + wn * 64 + nt * 16 + l16;
        float bias = bih[n] + bhh[n];
#pragma unroll
        for (int mt = 0; mt < 4; mt++) {
#pragma unroll
            for (int rr = 0; rr < 4; rr++) {
                int r = m0 + wm * 64 + mt * 16 + quad * 4 + rr;
                if (r < 4032) xg[(long)r * 2048 + n] = acc[mt][nt][rr] + bias;
            }
        }
    }
}

// ---------------- h0/c0 finalize: tanh(ps + bias) -> Hbuf[0] / c0buf ----------
__global__ __launch_bounds__(256) void k_fin(
    const float* ps, const float* bh, const float* bc,
    unsigned short* Hbuf, float* c0buf)
{
    int i = blockIdx.x * 256 + threadIdx.x;   // 65536 = 64 x 1024
    int m = i >> 10, ng = i & 1023;
    int j = ng & 511;
    float bias = (ng < 512) ? bh[j] : bc[j];
    float v = tanhf(ps[i] + bias);
    if (ng < 512) Hbuf[(long)m * 512 + j] = f2bf(v);
    else          c0buf[(long)m * 512 + j] = v;
}

// ---------------- scan: EXACT R0-proven lockstep (195 us) ---------------------
__global__ __launch_bounds__(256, 1) void k_scan(
    const unsigned short* Whh_b, const float* xg, const float* c0buf,
    unsigned short* Hbuf, int* ctrs)
{
    __shared__ unsigned short Wlds[128 * 520];  // 130 KB resident W_hh slice
    __shared__ unsigned short hs[16 * 520];     // staged h[s-1] (16 batches x 512)
    __shared__ float gs[16 * 133];              // gate exchange
    const int tid = threadIdx.x;
    const int gid = blockIdx.x;
    const int b0 = (gid & 3) * 16;   // batch group
    const int j0 = (gid >> 2) * 32;  // hidden-unit slice
    const int w = tid >> 6, lane = tid & 63, quad = lane >> 4, l16 = lane & 15;
    const int m = tid >> 4, u0 = (tid & 15) * 2;

    // resident W_hh slice: rows nrel = q*32+u  <->  W_hh row q*512 + j0 + u
    for (int nrel = w; nrel < 128; nrel += 4) {
        int q = nrel >> 5, u = nrel & 31;
        *(uint4*)&Wlds[nrel * 520 + lane * 8] =
            *(const uint4*)&Whh_b[(long)(q * 512 + j0 + u) * 512 + lane * 8];
    }
    float2 cr = *(const float2*)&c0buf[(long)(b0 + m) * 512 + j0 + u0];
    float c0v = cr.x, c1v = cr.y;
    int* ctr = ctrs + (gid & 3) * 64;
    __syncthreads();

    for (int s = 1; s < 64; s++) {
        // xg prefetch (read-only, normal cached loads)
        const float* xb = xg + ((long)(b0 + m) * 63 + (s - 1)) * 2048 + j0 + u0;
        float2 xv0 = *(const float2*)(xb + 0);
        float2 xv1 = *(const float2*)(xb + 512);
        float2 xv2 = *(const float2*)(xb + 1024);
        float2 xv3 = *(const float2*)(xb + 1536);

        // coherent staging of h[s-1]: 16 rows x 256 dwords, round j = row j
        const unsigned* hsrc = (const unsigned*)(Hbuf + ((long)(s - 1) * 64 + b0) * 512);
        unsigned hv[16];
#pragma unroll
        for (int j = 0; j < 16; j++)
            hv[j] = __hip_atomic_load(hsrc + j * 256 + tid, __ATOMIC_RELAXED,
                                      __HIP_MEMORY_SCOPE_AGENT);
#pragma unroll
        for (int j = 0; j < 16; j++)
            *(unsigned*)&hs[j * 520 + tid * 2] = hv[j];
        __syncthreads();

        f32x4 acc0 = (f32x4){0.f, 0.f, 0.f, 0.f};
        f32x4 acc1 = (f32x4){0.f, 0.f, 0.f, 0.f};
#pragma unroll
        for (int kk = 0; kk < 16; kk++) {
            bf16x8 a  = *(const bf16x8*)&hs[l16 * 520 + kk * 32 + quad * 8];
            bf16x8 bA = *(const bf16x8*)&Wlds[(32 * w + l16) * 520 + kk * 32 + quad * 8];
            bf16x8 bB = *(const bf16x8*)&Wlds[(32 * w + 16 + l16) * 520 + kk * 32 + quad * 8];
            acc0 = __builtin_amdgcn_mfma_f32_16x16x32_bf16(a, bA, acc0, 0, 0, 0);
            acc1 = __builtin_amdgcn_mfma_f32_16x16x32_bf16(a, bB, acc1, 0, 0, 0);
        }
#pragma unroll
        for (int rr = 0; rr < 4; rr++) {
            gs[(quad * 4 + rr) * 133 + 32 * w + l16] = acc0[rr];
            gs[(quad * 4 + rr) * 133 + 32 * w + 16 + l16] = acc1[rr];
        }
        __syncthreads();

        float gi0 = gs[m * 133 + u0]          + xv0.x;
        float gi1 = gs[m * 133 + u0 + 1]      + xv0.y;
        float gf0 = gs[m * 133 + 32 + u0]     + xv1.x;
        float gf1 = gs[m * 133 + 33 + u0]     + xv1.y;
        float gg0 = gs[m * 133 + 64 + u0]     + xv2.x;
        float gg1 = gs[m * 133 + 65 + u0]     + xv2.y;
        float go0 = gs[m * 133 + 96 + u0]     + xv3.x;
        float go1 = gs[m * 133 + 97 + u0]     + xv3.y;
        float cn0 = (1.f / (1.f + __expf(-gf0))) * c0v + (1.f / (1.f + __expf(-gi0))) * tanhf(gg0);
        float cn1 = (1.f / (1.f + __expf(-gf1))) * c1v + (1.f / (1.f + __expf(-gi1))) * tanhf(gg1);
        c0v = cn0; c1v = cn1;
        float h0v = (1.f / (1.f + __expf(-go0))) * tanhf(cn0);
        float h1v = (1.f / (1.f + __expf(-go1))) * tanhf(cn1);
        unsigned hp = (unsigned)f2bf(h0v) | ((unsigned)f2bf(h1v) << 16);
        __hip_atomic_store((unsigned*)(Hbuf + ((long)s * 64 + b0 + m) * 512 + j0 + u0), hp,
                           __ATOMIC_RELAXED, __HIP_MEMORY_SCOPE_AGENT);

        if (s < 63) {
            __syncthreads();   // all waves' h stores drained (vmcnt 0) before count
            if (tid == 0) {
                __hip_atomic_fetch_add(ctr, 1, __ATOMIC_RELEASE, __HIP_MEMORY_SCOPE_AGENT);
                int target = s * 16;
                while (__hip_atomic_load(ctr, __ATOMIC_RELAXED, __HIP_MEMORY_SCOPE_AGENT) < target) {}
            }
            __syncthreads();
        }
    }
}

// ---------------- logits: 128x128 tile + XCD-chunked n-major swizzle ----------
__global__ __launch_bounds__(256) void k_out(
    const unsigned short* A, const unsigned short* Wob, const float* bout, float* out)
{
    __shared__ unsigned short As[128 * 32];
    __shared__ unsigned short Bs[128 * 32];
    const int tid = threadIdx.x;
    // 2528 tiles = 8 XCDs x 316; n-major within chunk: Wout panel L2-resident
    const int tile = (blockIdx.x & 7) * 316 + (blockIdx.x >> 3);
    const int n0 = (tile >> 5) * 128, m0 = (tile & 31) * 128;
    const int w = tid >> 6, lane = tid & 63, quad = lane >> 4, l16 = lane & 15;
    const int wm = w >> 1, wn = w & 1;
    const int gr = lane >> 2, gc = (lane & 3) * 8;

    f32x4 acc[4][4];
#pragma unroll
    for (int i = 0; i < 4; i++)
#pragma unroll
        for (int j = 0; j < 4; j++) acc[i][j] = (f32x4){0.f, 0.f, 0.f, 0.f};

    for (int kb = 0; kb < 16; kb++) {
        int k0 = kb * 32;
#pragma unroll
        for (int p = 0; p < 2; p++) {
            int rowa = m0 + p * 64 + w * 16 + gr;
            GLD_LDS16(A + (long)rowa * 512 + k0 + gc, As + (p * 64 + w * 16) * 32);
            int rowb = n0 + p * 64 + w * 16 + gr;
            GLD_LDS16(Wob + (long)rowb * 512 + k0 + gc, Bs + (p * 64 + w * 16) * 32);
        }
        __syncthreads();
        bf16x8 af[4], bf[4];
#pragma unroll
        for (int mt = 0; mt < 4; mt++)
            af[mt] = *(const bf16x8*)&As[(wm * 64 + mt * 16 + l16) * 32 + quad * 8];
#pragma unroll
        for (int nt = 0; nt < 4; nt++)
            bf[nt] = *(const bf16x8*)&Bs[(wn * 64 + nt * 16 + l16) * 32 + quad * 8];
#pragma unroll
        for (int mt = 0; mt < 4; mt++)
#pragma unroll
            for (int nt = 0; nt < 4; nt++)
                acc[mt][nt] = __builtin_amdgcn_mfma_f32_16x16x32_bf16(af[mt], bf[nt], acc[mt][nt], 0, 0, 0);
        __syncthreads();
    }
#pragma unroll
    for (int nt = 0; nt < 4; nt++) {
        int n = n0 + wn * 64 + nt * 16 + l16;
        if (n >= 10000) continue;
        float bias = bout[n];
#pragma unroll
        for (int mt = 0; mt < 4; mt++) {
#pragma unroll
            for (int rr = 0; rr < 4; rr++) {
                int r = m0 + wm * 64 + mt * 16 + quad * 4 + rr;  // A row
                if (r < 4032) {
                    int s = (r >> 6) + 1, b = r & 63;
                    out[((long)b * 64 + s) * 10000 + n] = acc[mt][nt][rr] + bias;
                }
            }
        }
    }
}

extern "C" void kernel_launch(void* const* d_in, const int* in_sizes, int n_in,
                              void* d_out, int out_size, void* d_ws, size_t ws_size,
                              hipStream_t stream)
{
    const float* enc     = (const float*)d_in[0];
    const int*   targets = (const int*)d_in[1];
    const float* emb     = (const float*)d_in[2];
    const float* Wih     = (const float*)d_in[3];
    const float* Whh     = (const float*)d_in[4];
    const float* bih     = (const float*)d_in[5];
    const float* bhh     = (const float*)d_in[6];
    const float* Wh      = (const float*)d_in[7];
    const float* bh      = (const float*)d_in[8];
    const float* Wc      = (const float*)d_in[9];
    const float* bc      = (const float*)d_in[10];
    const float* Wout    = (const float*)d_in[11];
    const float* bout    = (const float*)d_in[12];
    float* out = (float*)d_out;

    char* ws = (char*)d_ws;
    size_t off = 0;
    auto alloc = [&](size_t bytes) {
        void* p = ws + off;
        off = (off + bytes + 255) & ~(size_t)255;
        return p;
    };
    unsigned short* mean_b = (unsigned short*)alloc((size_t)64 * 2048 * 2);
    unsigned short* Wih_b  = (unsigned short*)alloc((size_t)2048 * 512 * 2);
    unsigned short* Whh_b  = (unsigned short*)alloc((size_t)2048 * 512 * 2);
    unsigned short* Wh_b   = (unsigned short*)alloc((size_t)512 * 2048 * 2);
    unsigned short* Wc_b   = (unsigned short*)alloc((size_t)512 * 2048 * 2);
    unsigned short* Wout_b = (unsigned short*)alloc((size_t)10000 * 512 * 2);
    // +64 pad rows: 128-row staging tiles overread past row 4032 harmlessly
    unsigned short* Aemb   = (unsigned short*)alloc((size_t)(4032 + 64) * 512 * 2);
    float*          xg     = (float*)alloc((size_t)4032 * 2048 * 4);
    // +64 pad rows: k_out's A view (Hbuf+64*512) overreads past row 4095
    unsigned short* Hbuf   = (unsigned short*)alloc((size_t)(64 * 64 + 64) * 512 * 2);
    float*          c0buf  = (float*)alloc((size_t)64 * 512 * 4);
    int*            ctrs   = (int*)alloc(256 * 4);
    float*          ps     = (float*)alloc((size_t)64 * 1024 * 4);

    k_prep<<<6758, 256, 0, stream>>>(Wih, Whh, Wh, Wc, Wout, emb, targets, enc,
                                     Wih_b, Whh_b, Wh_b, Wc_b, Wout_b, Aemb,
                                     out, ctrs, ps, mean_b);
    k_gemm2<<<576, 256, 0, stream>>>(mean_b, Wh_b, Wc_b, ps,
                                     Aemb, Wih_b, bih, bhh, xg);
    k_fin<<<256, 256, 0, stream>>>(ps, bh, bc, Hbuf, c0buf);
    k_scan<<<64, 256, 0, stream>>>(Whh_b, xg, c0buf, Hbuf, ctrs);
    k_out<<<2528, 256, 0, stream>>>(Hbuf + 64 * 512, Wout_b, bout, out);
}